// Round 8
// baseline (330.341 us; speedup 1.0000x reference)
//
#include <hip/hip_runtime.h>

#define NE 8
#define TA 8192
#define MAXT 40
#define MAXPAD (MAXT*256)       // 10240

typedef __attribute__((ext_vector_type(4)))  float f32x4;
typedef __attribute__((ext_vector_type(16))) float f32x16;
typedef __attribute__((ext_vector_type(8)))  short s16x8;

// ws int-area layout (int indices)
#define WS_CUR  8    // [8]
#define WS_META 16   // [2] {ntiles, total_padded}
#define WS_TEXP 18   // [<=40]
#define WS_PERM 256  // [MAXPAD]

#define WAITVM(N) asm volatile("s_waitcnt vmcnt(" #N ")" ::: "memory")
#define BAR()     asm volatile("s_barrier" ::: "memory")

__device__ __forceinline__ unsigned short f2bf(float f) {
  unsigned u = __builtin_bit_cast(unsigned, f);
  u += 0x7FFFu + ((u >> 16) & 1u);   // RNE (inputs finite)
  return (unsigned short)(u >> 16);
}

__device__ __forceinline__ void glds16(const unsigned short* g, unsigned short* l) {
  __builtin_amdgcn_global_load_lds(
      (const __attribute__((address_space(1))) unsigned int*)g,
      (__attribute__((address_space(3))) unsigned int*)l, 16, 0, 0);
}

// ---------------- routing: single kernel (count, scan, init perm, place) ----------------
__global__ void k_route(const int* __restrict__ idx, int* __restrict__ ws) {
  __shared__ int cnt[NE];
  int t = threadIdx.x;                 // 1024 threads, 1 block
  if (t < NE) cnt[t] = 0;
  __syncthreads();
  int e0[8];
#pragma unroll
  for (int k = 0; k < 8; ++k) { e0[k] = idx[t + k * 1024]; atomicAdd(&cnt[e0[k]], 1); }
  __syncthreads();
  if (t == 0) {
    int off = 0, ti = 0;
    for (int e = 0; e < NE; ++e) {
      ws[WS_CUR + e] = off;
      int c = cnt[e];
      int ntl = (c + 255) >> 8;
      for (int k = 0; k < ntl; ++k) ws[WS_TEXP + ti++] = e;
      off += ntl << 8;
    }
    ws[WS_META] = ti;
    ws[WS_META + 1] = off;
  }
#pragma unroll
  for (int k = 0; k < MAXPAD / 1024; ++k) ws[WS_PERM + t + k * 1024] = -1;
  __syncthreads();
#pragma unroll
  for (int k = 0; k < 8; ++k) {
    int p = atomicAdd(&ws[WS_CUR + e0[k]], 1);
    ws[WS_PERM + p] = t + k * 1024;
  }
}

// ---------------- fused gate+up convert with 32-row interleave ----------------
// dest row (per expert, 4096 rows): (h>>5)*64 + (h&31) gate, +32 up
__global__ void k_cvt_gu2(const float* __restrict__ g, const float* __restrict__ u,
                          unsigned short* __restrict__ d) {
  int t = blockIdx.x * 256 + threadIdx.x;
  int i = t * 8;
  int dd = i & 1023;
  int h = (i >> 10) & 2047;
  int e = i >> 21;
  int dr = (e << 12) + ((h >> 5) << 6) + (h & 31);
  f32x4 a = *(const f32x4*)(g + i);
  f32x4 b = *(const f32x4*)(g + i + 4);
  s16x8 o;
  o[0] = (short)f2bf(a[0]); o[1] = (short)f2bf(a[1]);
  o[2] = (short)f2bf(a[2]); o[3] = (short)f2bf(a[3]);
  o[4] = (short)f2bf(b[0]); o[5] = (short)f2bf(b[1]);
  o[6] = (short)f2bf(b[2]); o[7] = (short)f2bf(b[3]);
  *(s16x8*)(d + (size_t)dr * 1024 + dd) = o;
  a = *(const f32x4*)(u + i);
  b = *(const f32x4*)(u + i + 4);
  o[0] = (short)f2bf(a[0]); o[1] = (short)f2bf(a[1]);
  o[2] = (short)f2bf(a[2]); o[3] = (short)f2bf(a[3]);
  o[4] = (short)f2bf(b[0]); o[5] = (short)f2bf(b[1]);
  o[6] = (short)f2bf(b[2]); o[7] = (short)f2bf(b[3]);
  *(s16x8*)(d + (size_t)(dr + 32) * 1024 + dd) = o;
}

// ---------------- plain f32 -> bf16 convert (w_down) ----------------
__global__ void k_cvt(const float* __restrict__ s, unsigned short* __restrict__ d) {
  int i = (blockIdx.x * 256 + threadIdx.x) * 8;
  f32x4 a = *(const f32x4*)(s + i);
  f32x4 b = *(const f32x4*)(s + i + 4);
  s16x8 o;
  o[0] = (short)f2bf(a[0]); o[1] = (short)f2bf(a[1]);
  o[2] = (short)f2bf(a[2]); o[3] = (short)f2bf(a[3]);
  o[4] = (short)f2bf(b[0]); o[5] = (short)f2bf(b[1]);
  o[6] = (short)f2bf(b[2]); o[7] = (short)f2bf(b[3]);
  *(s16x8*)(d + i) = o;
}

// ---------------- gather x rows (permuted, bf16, zero pads) ----------------
__global__ void k_gather(const float* __restrict__ x, const int* __restrict__ ws,
                         unsigned short* __restrict__ xb) {
  int tid = blockIdx.x * 256 + threadIdx.x;
  int r = tid >> 7;
  int c = (tid & 127) << 3;
  int ta = ws[WS_PERM + r];
  s16x8 o = {0,0,0,0,0,0,0,0};
  if (ta >= 0) {
    const float* xp = x + (size_t)(ta >> 1) * 1024 + c;
    f32x4 a = *(const f32x4*)xp;
    f32x4 b = *(const f32x4*)(xp + 4);
    o[0] = (short)f2bf(a[0]); o[1] = (short)f2bf(a[1]);
    o[2] = (short)f2bf(a[2]); o[3] = (short)f2bf(a[3]);
    o[4] = (short)f2bf(b[0]); o[5] = (short)f2bf(b[1]);
    o[6] = (short)f2bf(b[2]); o[7] = (short)f2bf(b[3]);
  }
  *(s16x8*)(xb + (size_t)r * 1024 + c) = o;
}

// LDS tile layout per matrix (32KB = 16384 elems): [khalf h][256 rows][4 chunks of 16B]
//   elem(row, kc):  h=kc>>2, cl=kc&3, phys = h*8192 + row*32 + ((cl ^ (row&3))<<3)
// Stage group (matrix, h, rowhalf rh) = one 8KB glds: thread -> row rl=tid>>2 (+rh*128),
//   phys chunk tid&3, src chunk (tid&3)^(rl&3).

// stage both matrices' half H of tile at k-offset K0 into buffer LB (4 glds issues)
#define STG(LB, H, K0, RSTEP)                                          \
  {                                                                    \
    unsigned short* Ld = (LB) + (H) * 8192 + tid * 8;                  \
    int ko = (K0) + (H) * 32;                                          \
    glds16(gAs + ko,           Ld);                                    \
    glds16(gAs + ko + (RSTEP), Ld + 4096);                             \
    glds16(gBs + ko,           Ld + 16384);                            \
    glds16(gBs + ko + (RSTEP), Ld + 16384 + 4096);                     \
  }

// ---------------- GEMM1: 256x256 tile, 32x32x16 MFMA, fused gate/up ----------------
__global__ __launch_bounds__(512) void k_gemm1(
    const unsigned short* __restrict__ xb, const unsigned short* __restrict__ wgu,
    unsigned short* __restrict__ hb, const int* __restrict__ ws) {
  int mt = blockIdx.y;
  if (mt >= ws[WS_META]) return;
  int e = ws[WS_TEXP + mt];
  int nt = blockIdx.x;   // 0..15

  __shared__ unsigned short L[2][32768];   // [A 16384 | B 16384] per buf; 128KB

  int tid = threadIdx.x;
  int lane = tid & 63, wid = tid >> 6;
  int wm = wid >> 2, wn = wid & 3;         // 2M x 4N
  int r31 = lane & 31, kg = lane >> 5, x3 = r31 & 3;

  int rl  = tid >> 2;                      // staging row 0..127
  int csw = (tid & 3) ^ (rl & 3);          // source chunk-in-half

  const unsigned short* gAs = xb  + (size_t)(mt * 256 + rl) * 1024 + csw * 8;
  const unsigned short* gBs = wgu + (size_t)(e * 4096 + nt * 256 + rl) * 1024 + csw * 8;

  f32x16 accg[4] = {};
  f32x16 accu[4] = {};

  int aof0 = (wm * 128 + r31) * 32;
  int aof1 = aof0 + 1024;
  int aof2 = aof0 + 2048;
  int aof3 = aof0 + 3072;
  int bgo  = (wn * 64 + r31) * 32;

#define CMP1(LC, P)                                                          \
  {                                                                          \
    const unsigned short* Ab = (LC) + (P) * 8192;                            \
    const unsigned short* Bb = Ab + 16384;                                   \
    _Pragma("unroll")                                                        \
    for (int ksl = 0; ksl < 2; ++ksl) {                                      \
      int sc = ((kg + 2 * ksl) ^ x3) << 3;                                   \
      s16x8 a0 = *(const s16x8*)&Ab[aof0 + sc];                              \
      s16x8 a1 = *(const s16x8*)&Ab[aof1 + sc];                              \
      s16x8 a2 = *(const s16x8*)&Ab[aof2 + sc];                              \
      s16x8 a3 = *(const s16x8*)&Ab[aof3 + sc];                              \
      s16x8 bg = *(const s16x8*)&Bb[bgo + sc];                               \
      s16x8 bu = *(const s16x8*)&Bb[bgo + 1024 + sc];                        \
      __builtin_amdgcn_s_setprio(1);                                         \
      accg[0] = __builtin_amdgcn_mfma_f32_32x32x16_bf16(a0, bg, accg[0], 0,0,0); \
      accu[0] = __builtin_amdgcn_mfma_f32_32x32x16_bf16(a0, bu, accu[0], 0,0,0); \
      accg[1] = __builtin_amdgcn_mfma_f32_32x32x16_bf16(a1, bg, accg[1], 0,0,0); \
      accu[1] = __builtin_amdgcn_mfma_f32_32x32x16_bf16(a1, bu, accu[1], 0,0,0); \
      accg[2] = __builtin_amdgcn_mfma_f32_32x32x16_bf16(a2, bg, accg[2], 0,0,0); \
      accu[2] = __builtin_amdgcn_mfma_f32_32x32x16_bf16(a2, bu, accu[2], 0,0,0); \
      accg[3] = __builtin_amdgcn_mfma_f32_32x32x16_bf16(a3, bg, accg[3], 0,0,0); \
      accu[3] = __builtin_amdgcn_mfma_f32_32x32x16_bf16(a3, bu, accu[3], 0,0,0); \
      __builtin_amdgcn_s_setprio(0);                                         \
    }                                                                        \
  }

  STG(&L[0][0], 0, 0, 131072)
  STG(&L[0][0], 1, 0, 131072)

#pragma unroll 2
  for (int kt = 0; kt < 16; ++kt) {
    unsigned short* Lc = &L[kt & 1][0];
    unsigned short* Ln = &L[(kt & 1) ^ 1][0];
    int kn = (kt + 1 < 16 ? kt + 1 : kt) * 64;   // clamped dummy keeps vmcnt exact
    WAITVM(4); BAR();
    STG(Ln, 0, kn, 131072)
    CMP1(Lc, 0)
    WAITVM(4); BAR();
    STG(Ln, 1, kn, 131072)
    CMP1(Lc, 1)
  }
  WAITVM(0);

  // epilogue: C 32x32: col=lane&31, row=(r&3)+8*(r>>2)+4*(lane>>5)
  int hrow0 = mt * 256 + wm * 128;
  int hcol  = nt * 128 + wn * 32 + r31;
#pragma unroll
  for (int mi = 0; mi < 4; ++mi)
#pragma unroll
    for (int r = 0; r < 16; ++r) {
      int crow = (r & 3) + 8 * (r >> 2) + 4 * kg;
      float g = accg[mi][r];
      float u = accu[mi][r];
      float h = (g / (1.f + __expf(-g))) * u;
      hb[(size_t)(hrow0 + mi * 32 + crow) * 2048 + hcol] = f2bf(h);
    }
}

// ---------------- GEMM2: 256x256 tile, split-K=2, atomic f32 scatter ----------------
__global__ __launch_bounds__(512) void k_gemm2(
    const unsigned short* __restrict__ hb, const unsigned short* __restrict__ wdb,
    float* __restrict__ out, const int* __restrict__ ws) {
  int mt = blockIdx.y;
  if (mt >= ws[WS_META]) return;
  int e = ws[WS_TEXP + mt];
  int nt = blockIdx.x & 3;
  int kslice = blockIdx.x >> 2;            // 0/1, each 16 K-tiles of 32
  int kb = kslice * 1024;

  __shared__ unsigned short L[2][32768];

  int tid = threadIdx.x;
  int lane = tid & 63, wid = tid >> 6;
  int wm = wid >> 2, wn = wid & 3;
  int r31 = lane & 31, kg = lane >> 5, x3 = r31 & 3;

  int rl  = tid >> 2;
  int csw = (tid & 3) ^ (rl & 3);

  const unsigned short* gAs = hb  + (size_t)(mt * 256 + rl) * 2048 + kb + csw * 8;
  const unsigned short* gBs = wdb + (size_t)(e * 1024 + nt * 256 + rl) * 2048 + kb + csw * 8;

  f32x16 acc0[4] = {};
  f32x16 acc1[4] = {};

  int aof0 = (wm * 128 + r31) * 32;
  int aof1 = aof0 + 1024;
  int aof2 = aof0 + 2048;
  int aof3 = aof0 + 3072;
  int bgo  = (wn * 64 + r31) * 32;

#define CMP2(LC, P)                                                          \
  {                                                                          \
    const unsigned short* Ab = (LC) + (P) * 8192;                            \
    const unsigned short* Bb = Ab + 16384;                                   \
    _Pragma("unroll")                                                        \
    for (int ksl = 0; ksl < 2; ++ksl) {                                      \
      int sc = ((kg + 2 * ksl) ^ x3) << 3;                                   \
      s16x8 a0 = *(const s16x8*)&Ab[aof0 + sc];                              \
      s16x8 a1 = *(const s16x8*)&Ab[aof1 + sc];                              \
      s16x8 a2 = *(const s16x8*)&Ab[aof2 + sc];                              \
      s16x8 a3 = *(const s16x8*)&Ab[aof3 + sc];                              \
      s16x8 b0 = *(const s16x8*)&Bb[bgo + sc];                               \
      s16x8 b1 = *(const s16x8*)&Bb[bgo + 1024 + sc];                        \
      __builtin_amdgcn_s_setprio(1);                                         \
      acc0[0] = __builtin_amdgcn_mfma_f32_32x32x16_bf16(a0, b0, acc0[0], 0,0,0); \
      acc1[0] = __builtin_amdgcn_mfma_f32_32x32x16_bf16(a0, b1, acc1[0], 0,0,0); \
      acc0[1] = __builtin_amdgcn_mfma_f32_32x32x16_bf16(a1, b0, acc0[1], 0,0,0); \
      acc1[1] = __builtin_amdgcn_mfma_f32_32x32x16_bf16(a1, b1, acc1[1], 0,0,0); \
      acc0[2] = __builtin_amdgcn_mfma_f32_32x32x16_bf16(a2, b0, acc0[2], 0,0,0); \
      acc1[2] = __builtin_amdgcn_mfma_f32_32x32x16_bf16(a2, b1, acc1[2], 0,0,0); \
      acc0[3] = __builtin_amdgcn_mfma_f32_32x32x16_bf16(a3, b0, acc0[3], 0,0,0); \
      acc1[3] = __builtin_amdgcn_mfma_f32_32x32x16_bf16(a3, b1, acc1[3], 0,0,0); \
      __builtin_amdgcn_s_setprio(0);                                         \
    }                                                                        \
  }

  STG(&L[0][0], 0, 0, 262144)
  STG(&L[0][0], 1, 0, 262144)

#pragma unroll 2
  for (int kt = 0; kt < 16; ++kt) {
    unsigned short* Lc = &L[kt & 1][0];
    unsigned short* Ln = &L[(kt & 1) ^ 1][0];
    int kn = (kt + 1 < 16 ? kt + 1 : kt) * 64;
    WAITVM(4); BAR();
    STG(Ln, 0, kn, 262144)
    CMP2(Lc, 0)
    WAITVM(4); BAR();
    STG(Ln, 1, kn, 262144)
    CMP2(Lc, 1)
  }
  WAITVM(0);

  int prow0 = mt * 256 + wm * 128;
  int dcol  = nt * 256 + wn * 64 + r31;
#pragma unroll
  for (int mi = 0; mi < 4; ++mi)
#pragma unroll
    for (int r = 0; r < 16; ++r) {
      int crow = (r & 3) + 8 * (r >> 2) + 4 * kg;
      int ta = ws[WS_PERM + prow0 + mi * 32 + crow];
      if (ta >= 0) {
        unsafeAtomicAdd(&out[(size_t)ta * 1024 + dcol],      acc0[mi][r]);
        unsafeAtomicAdd(&out[(size_t)ta * 1024 + dcol + 32], acc1[mi][r]);
      }
    }
}

extern "C" void kernel_launch(void* const* d_in, const int* in_sizes, int n_in,
                              void* d_out, int out_size, void* d_ws, size_t ws_size,
                              hipStream_t stream) {
  const float* x   = (const float*)d_in[0];
  const int*   idx = (const int*)d_in[1];
  const float* wg  = (const float*)d_in[2];
  const float* wu  = (const float*)d_in[3];
  const float* wd  = (const float*)d_in[4];
  float* out = (float*)d_out;

  int*  wsi = (int*)d_ws;
  char* wsb = (char*)d_ws;
  // xb and wdb OVERLAY (xb dead after gemm1; cvt_wd runs after gemm1)
  const size_t OFF_XB  = 65536;
  const size_t OFF_WDB = 65536;
  const size_t OFF_WGU = 65536 + (size_t)NE * 1024 * 2048 * 2;
  const size_t OFF_HB  = OFF_WGU + (size_t)NE * 4096 * 1024 * 2;
  unsigned short* xbuf = (unsigned short*)(wsb + OFF_XB);
  unsigned short* wdb  = (unsigned short*)(wsb + OFF_WDB);
  unsigned short* wgu  = (unsigned short*)(wsb + OFF_WGU);
  unsigned short* hb   = (unsigned short*)(wsb + OFF_HB);

  k_route<<<1, 1024, 0, stream>>>(idx, wsi);
  k_cvt_gu2<<<(NE * 2048 * 1024) / (256 * 8), 256, 0, stream>>>(wg, wu, wgu);
  k_gather<<<(MAXPAD * 128) / 256, 256, 0, stream>>>(x, wsi, xbuf);

  k_gemm1<<<dim3(16, MAXT), 512, 0, stream>>>(xbuf, wgu, hb, wsi);

  k_cvt<<<(NE * 1024 * 2048) / (256 * 8), 256, 0, stream>>>(wd, wdb);   // overlay after gemm1

  hipMemsetAsync(out, 0, (size_t)out_size * sizeof(float), stream);     // atomics accumulate
  k_gemm2<<<dim3(8, MAXT), 512, 0, stream>>>(hb, wdb, out, wsi);
}

// Round 9
// 266.411 us; speedup vs baseline: 1.2400x; 1.2400x over previous
//
#include <hip/hip_runtime.h>

#define NE 8
#define TA 8192
#define MAXT 40
#define MAXPAD (MAXT*256)       // 10240

typedef __attribute__((ext_vector_type(4)))  float f32x4;
typedef __attribute__((ext_vector_type(16))) float f32x16;
typedef __attribute__((ext_vector_type(8)))  short s16x8;

// ws int-area layout (int indices)
#define WS_CUR  8    // [8]
#define WS_META 16   // [2] {ntiles256, total_padded}
#define WS_TEXP 18   // [<=40]
#define WS_PERM 256  // [MAXPAD]

#define WAITVM(N) asm volatile("s_waitcnt vmcnt(" #N ")" ::: "memory")
#define LGKM0()   asm volatile("s_waitcnt lgkmcnt(0)" ::: "memory")
#define BAR()     asm volatile("s_barrier" ::: "memory")

__device__ __forceinline__ unsigned short f2bf(float f) {
  unsigned u = __builtin_bit_cast(unsigned, f);
  u += 0x7FFFu + ((u >> 16) & 1u);   // RNE (inputs finite)
  return (unsigned short)(u >> 16);
}

__device__ __forceinline__ void glds16(const unsigned short* g, unsigned short* l) {
  __builtin_amdgcn_global_load_lds(
      (const __attribute__((address_space(1))) unsigned int*)g,
      (__attribute__((address_space(3))) unsigned int*)l, 16, 0, 0);
}

// ---------------- routing: single kernel ----------------
__global__ void k_route(const int* __restrict__ idx, int* __restrict__ ws) {
  __shared__ int cnt[NE];
  int t = threadIdx.x;                 // 1024 threads, 1 block
  if (t < NE) cnt[t] = 0;
  __syncthreads();
  int e0[8];
#pragma unroll
  for (int k = 0; k < 8; ++k) { e0[k] = idx[t + k * 1024]; atomicAdd(&cnt[e0[k]], 1); }
  __syncthreads();
  if (t == 0) {
    int off = 0, ti = 0;
    for (int e = 0; e < NE; ++e) {
      ws[WS_CUR + e] = off;
      int c = cnt[e];
      int ntl = (c + 255) >> 8;
      for (int k = 0; k < ntl; ++k) ws[WS_TEXP + ti++] = e;
      off += ntl << 8;
    }
    ws[WS_META] = ti;
    ws[WS_META + 1] = off;
  }
#pragma unroll
  for (int k = 0; k < MAXPAD / 1024; ++k) ws[WS_PERM + t + k * 1024] = -1;
  __syncthreads();
#pragma unroll
  for (int k = 0; k < 8; ++k) {
    int p = atomicAdd(&ws[WS_CUR + e0[k]], 1);
    ws[WS_PERM + p] = t + k * 1024;
  }
}

// ---------------- fused gate+up convert, 32-row interleave ----------------
__global__ void k_cvt_gu2(const float* __restrict__ g, const float* __restrict__ u,
                          unsigned short* __restrict__ d) {
  int t = blockIdx.x * 256 + threadIdx.x;
  int i = t * 8;
  int dd = i & 1023;
  int h = (i >> 10) & 2047;
  int e = i >> 21;
  int dr = (e << 12) + ((h >> 5) << 6) + (h & 31);
  f32x4 a = *(const f32x4*)(g + i);
  f32x4 b = *(const f32x4*)(g + i + 4);
  s16x8 o;
  o[0] = (short)f2bf(a[0]); o[1] = (short)f2bf(a[1]);
  o[2] = (short)f2bf(a[2]); o[3] = (short)f2bf(a[3]);
  o[4] = (short)f2bf(b[0]); o[5] = (short)f2bf(b[1]);
  o[6] = (short)f2bf(b[2]); o[7] = (short)f2bf(b[3]);
  *(s16x8*)(d + (size_t)dr * 1024 + dd) = o;
  a = *(const f32x4*)(u + i);
  b = *(const f32x4*)(u + i + 4);
  o[0] = (short)f2bf(a[0]); o[1] = (short)f2bf(a[1]);
  o[2] = (short)f2bf(a[2]); o[3] = (short)f2bf(a[3]);
  o[4] = (short)f2bf(b[0]); o[5] = (short)f2bf(b[1]);
  o[6] = (short)f2bf(b[2]); o[7] = (short)f2bf(b[3]);
  *(s16x8*)(d + (size_t)(dr + 32) * 1024 + dd) = o;
}

// ---------------- plain f32 -> bf16 (w_down) ----------------
__global__ void k_cvt(const float* __restrict__ s, unsigned short* __restrict__ d) {
  int i = (blockIdx.x * 256 + threadIdx.x) * 8;
  f32x4 a = *(const f32x4*)(s + i);
  f32x4 b = *(const f32x4*)(s + i + 4);
  s16x8 o;
  o[0] = (short)f2bf(a[0]); o[1] = (short)f2bf(a[1]);
  o[2] = (short)f2bf(a[2]); o[3] = (short)f2bf(a[3]);
  o[4] = (short)f2bf(b[0]); o[5] = (short)f2bf(b[1]);
  o[6] = (short)f2bf(b[2]); o[7] = (short)f2bf(b[3]);
  *(s16x8*)(d + i) = o;
}

// ---------------- gather x rows ----------------
__global__ void k_gather(const float* __restrict__ x, const int* __restrict__ ws,
                         unsigned short* __restrict__ xb) {
  int tid = blockIdx.x * 256 + threadIdx.x;
  int r = tid >> 7;
  int c = (tid & 127) << 3;
  int ta = ws[WS_PERM + r];
  s16x8 o = {0,0,0,0,0,0,0,0};
  if (ta >= 0) {
    const float* xp = x + (size_t)(ta >> 1) * 1024 + c;
    f32x4 a = *(const f32x4*)xp;
    f32x4 b = *(const f32x4*)(xp + 4);
    o[0] = (short)f2bf(a[0]); o[1] = (short)f2bf(a[1]);
    o[2] = (short)f2bf(a[2]); o[3] = (short)f2bf(a[3]);
    o[4] = (short)f2bf(b[0]); o[5] = (short)f2bf(b[1]);
    o[6] = (short)f2bf(b[2]); o[7] = (short)f2bf(b[3]);
  }
  *(s16x8*)(xb + (size_t)r * 1024 + c) = o;
}

// ================= pipelined 128x128 GEMM core =================
// 512 thr (8 waves 4M x 2N), BM=128, BN=128 (B stored as rows, B^T GEMM),
// BK=64 in two 32-k phases. LDS/buffer = 32KB: A [2ksh][128r][32k] | B same.
// Per phase: WAITVM(2), BAR, stage next tile same-ksh (2 glds), 6 ds_read,
// 4 MFMA 32x32x16, BAR. Loads get 2 phases of slack; never drained.
// Swizzle: phys slot p holds k-chunk p^((r>>1)&3)  (period-8 bank walk).

// stage phase: 1 glds for A + 1 for B into buffer BUF, k-half KSH, k-offset KO
#define STG(BUF, KSH, KO)                                              \
  {                                                                    \
    unsigned short* ld = &L[BUF][(KSH) * 4096 + tid * 8];              \
    glds16(gA + (KO), ld);                                             \
    glds16(gB + (KO), ld + 8192);                                      \
  }

#define PHASE(BUF, KSH, KON, ACC0, ACC1)                               \
  {                                                                    \
    WAITVM(2);                                                         \
    BAR();                                                             \
    STG((BUF) ^ 1, KSH, KON);                                          \
    const unsigned short* Lb = &L[BUF][(KSH) * 4096];                  \
    s16x8 a0 = *(const s16x8*)&Lb[aoff + sca0];                        \
    s16x8 a1 = *(const s16x8*)&Lb[aoff + sca1];                        \
    s16x8 b00 = *(const s16x8*)&Lb[boff + scb0];                       \
    s16x8 b01 = *(const s16x8*)&Lb[boff + 1024 + scb0];                \
    s16x8 b10 = *(const s16x8*)&Lb[boff + scb1];                       \
    s16x8 b11 = *(const s16x8*)&Lb[boff + 1024 + scb1];                \
    __builtin_amdgcn_s_setprio(1);                                     \
    ACC0 = __builtin_amdgcn_mfma_f32_32x32x16_bf16(a0, b00, ACC0, 0, 0, 0); \
    ACC1 = __builtin_amdgcn_mfma_f32_32x32x16_bf16(a0, b01, ACC1, 0, 0, 0); \
    ACC0 = __builtin_amdgcn_mfma_f32_32x32x16_bf16(a1, b10, ACC0, 0, 0, 0); \
    ACC1 = __builtin_amdgcn_mfma_f32_32x32x16_bf16(a1, b11, ACC1, 0, 0, 0); \
    __builtin_amdgcn_s_setprio(0);                                     \
    LGKM0();                                                           \
    BAR();                                                             \
  }

// common per-thread geometry (inside kernel body after tid/lane setup):
#define GEOM_COMMON                                                    \
  int tid = threadIdx.x, lane = tid & 63, wid = tid >> 6;              \
  int wm = wid >> 1, wn = wid & 1;                                     \
  int r31 = lane & 31, kg = lane >> 5;                                 \
  int sr = tid >> 2, sp = tid & 3;                                     \
  int ss = sp ^ ((sr >> 1) & 3);                                       \
  int ra = wm * 32 + r31;                                              \
  int rb = wn * 64 + r31;                                              \
  int swa = (ra >> 1) & 3, swb = (rb >> 1) & 3;                        \
  int aoff = ra * 32;                                                  \
  int boff = 8192 + rb * 32;                                           \
  int sca0 = ((kg ^ swa)) << 3, sca1 = (((2 | kg) ^ swa)) << 3;        \
  int scb0 = ((kg ^ swb)) << 3, scb1 = (((2 | kg) ^ swb)) << 3;

// ---------------- GEMM1: h = silu(x@Wg^T)*(x@Wu^T), fused ----------------
__global__ __launch_bounds__(512, 4) void k_gemm1(
    const unsigned short* __restrict__ xb, const unsigned short* __restrict__ wgu,
    unsigned short* __restrict__ hb, const int* __restrict__ ws) {
  int mt = blockIdx.y;                  // 128-row tile, 0..79
  if (mt >= ws[WS_META] * 2) return;
  int e = ws[WS_TEXP + (mt >> 1)];
  int nt = blockIdx.x;                  // 0..31 (64 h-cols each)

  __shared__ unsigned short L[2][16384];   // 64KB total

  GEOM_COMMON

  const unsigned short* gA = xb  + (size_t)(mt * 128 + sr) * 1024 + ss * 8;
  const unsigned short* gB = wgu + (size_t)(e * 4096 + nt * 128 + sr) * 1024 + ss * 8;

  f32x16 accg = {}, accu = {};

  STG(0, 0, 0)
  STG(0, 1, 32)

#pragma unroll 2
  for (int t = 0; t < 16; ++t) {
    int tn = (t + 1 < 16 ? t + 1 : t) * 64;
    PHASE(t & 1, 0, tn,      accg, accu)
    PHASE(t & 1, 1, tn + 32, accg, accu)
  }

  int hrow0 = mt * 128 + wm * 32;
  int hcol  = (nt * 2 + wn) * 32 + r31;
#pragma unroll
  for (int r = 0; r < 16; ++r) {
    int crow = (r & 3) + 8 * (r >> 2) + 4 * kg;
    float g = accg[r];
    float u = accu[r];
    float h = (g / (1.f + __expf(-g))) * u;
    hb[(size_t)(hrow0 + crow) * 2048 + hcol] = f2bf(h);
  }
}

// ---------------- GEMM2: out = h @ Wd^T, scatter ----------------
__global__ __launch_bounds__(512, 4) void k_gemm2(
    const unsigned short* __restrict__ hb, const unsigned short* __restrict__ wdb,
    float* __restrict__ out, const int* __restrict__ ws) {
  int mt = blockIdx.y;                  // 0..79
  if (mt >= ws[WS_META] * 2) return;
  int e = ws[WS_TEXP + (mt >> 1)];
  int nt = blockIdx.x;                  // 0..7 (128 d-cols each)

  __shared__ unsigned short L[2][16384];

  GEOM_COMMON

  const unsigned short* gA = hb  + (size_t)(mt * 128 + sr) * 2048 + ss * 8;
  const unsigned short* gB = wdb + (size_t)(e * 1024 + nt * 128 + sr) * 2048 + ss * 8;

  f32x16 acc0 = {}, acc1 = {};

  STG(0, 0, 0)
  STG(0, 1, 32)

#pragma unroll 2
  for (int t = 0; t < 32; ++t) {
    int tn = (t + 1 < 32 ? t + 1 : t) * 64;
    PHASE(t & 1, 0, tn,      acc0, acc1)
    PHASE(t & 1, 1, tn + 32, acc0, acc1)
  }

  int prow0 = mt * 128 + wm * 32;
  int dcol  = nt * 128 + wn * 64 + r31;
#pragma unroll
  for (int r = 0; r < 16; ++r) {
    int crow = (r & 3) + 8 * (r >> 2) + 4 * kg;
    int ta = ws[WS_PERM + prow0 + crow];
    if (ta >= 0) {
      out[(size_t)ta * 1024 + dcol]      = acc0[r];
      out[(size_t)ta * 1024 + dcol + 32] = acc1[r];
    }
  }
}

extern "C" void kernel_launch(void* const* d_in, const int* in_sizes, int n_in,
                              void* d_out, int out_size, void* d_ws, size_t ws_size,
                              hipStream_t stream) {
  const float* x   = (const float*)d_in[0];
  const int*   idx = (const int*)d_in[1];
  const float* wg  = (const float*)d_in[2];
  const float* wu  = (const float*)d_in[3];
  const float* wd  = (const float*)d_in[4];
  float* out = (float*)d_out;

  int*  wsi = (int*)d_ws;
  char* wsb = (char*)d_ws;
  // xb and wdb OVERLAY (xb dead after gemm1; cvt_wd runs after gemm1)
  const size_t OFF_XB  = 65536;
  const size_t OFF_WDB = 65536;
  const size_t OFF_WGU = 65536 + (size_t)NE * 1024 * 2048 * 2;
  const size_t OFF_HB  = OFF_WGU + (size_t)NE * 4096 * 1024 * 2;
  unsigned short* xbuf = (unsigned short*)(wsb + OFF_XB);
  unsigned short* wdb  = (unsigned short*)(wsb + OFF_WDB);
  unsigned short* wgu  = (unsigned short*)(wsb + OFF_WGU);
  unsigned short* hb   = (unsigned short*)(wsb + OFF_HB);

  k_route<<<1, 1024, 0, stream>>>(idx, wsi);
  k_cvt_gu2<<<(NE * 2048 * 1024) / (256 * 8), 256, 0, stream>>>(wg, wu, wgu);
  k_gather<<<(MAXPAD * 128) / 256, 256, 0, stream>>>(x, wsi, xbuf);

  k_gemm1<<<dim3(32, MAXT * 2), 512, 0, stream>>>(xbuf, wgu, hb, wsi);

  k_cvt<<<(NE * 1024 * 2048) / (256 * 8), 256, 0, stream>>>(wd, wdb);   // overlay after gemm1

  k_gemm2<<<dim3(8, MAXT * 2), 512, 0, stream>>>(hb, wdb, out, wsi);
}